// Round 4
// baseline (80.103 us; speedup 1.0000x reference)
//
#include <hip/hip_runtime.h>

#define NG 14
#define NE 16
#define BW 4            // wafers per block (same expert)
#define FSTR 132        // per-group stride in feat/y buffer (floats)
#define ZSTR 116
#define WTSTR 76

// ws int layout: [0..15] counts, [16..32] offsets(17), [48..63] cursors, [64..] sorted ids

__device__ __forceinline__ float dot8(const float4 wa, const float4 wb,
                                      const float4 ya, const float4 yb) {
    return wa.x*ya.x + wa.y*ya.y + wa.z*ya.z + wa.w*ya.w
         + wb.x*yb.x + wb.y*yb.y + wb.z*yb.z + wb.w*yb.w;
}

__global__ void hist_kernel(const int* __restrict__ keys, int N, int* __restrict__ ws) {
    __shared__ int hc[NE];
    const int t = threadIdx.x;
    if (t < NE) hc[t] = 0;
    __syncthreads();
    const int i = blockIdx.x * 256 + t;
    if (i < N) atomicAdd(&hc[keys[i]], 1);
    __syncthreads();
    if (t < NE) atomicAdd(&ws[t], hc[t]);
}

__global__ void scan_kernel(int* __restrict__ ws) {
    if (threadIdx.x == 0) {
        int run = 0;
        for (int e = 0; e < NE; ++e) {
            ws[16 + e] = run;
            run += (ws[e] + BW - 1) & ~(BW - 1);   // pad each bin to multiple of BW
        }
        ws[16 + NE] = run;
    }
}

__global__ void scatter_kernel(const int* __restrict__ keys, int N, int* __restrict__ ws) {
    const int i = blockIdx.x * 256 + threadIdx.x;
    if (i < N) {
        const int e = keys[i];
        const int pos = atomicAdd(&ws[48 + e], 1);
        ws[64 + ws[16 + e] + pos] = i;
    }
}

__global__ __launch_bounds__(256, 3) void ae_main(
    const float* __restrict__ x,
    const int*   __restrict__ keys,
    const float* __restrict__ conv_mask,
    const float* __restrict__ enc_conv_w,
    const float* __restrict__ enc_dense_w,
    const float* __restrict__ enc_dense_b,
    const float* __restrict__ dec_dense_w,
    const float* __restrict__ dec_dense_b,
    const float* __restrict__ dec_tconv_w,
    const float* __restrict__ dec_tconv_b,
    const int*   __restrict__ ws,
    float* __restrict__ out)
{
    const int t = threadIdx.x;

    __shared__ float feat[BW][NG * FSTR];   // conv+pool feat, then reused for y [g][p*8+c]
    __shared__ float zsb[BW][ZSTR];
    __shared__ float wcs[1008];             // masked enc conv w
    __shared__ float wtr[NG * WTSTR];       // tconv w transposed [g][tap*8+c]
    __shared__ float decb[1792];
    __shared__ float encb[112];
    __shared__ float tcb[NG];
    __shared__ int ids[BW];
    __shared__ int kblk;

    const int* sorted = ws + 64;
    if (t < BW) ids[t] = sorted[blockIdx.x * BW + t];
    __syncthreads();
    if (t == 0) kblk = (ids[0] >= 0) ? keys[ids[0]] : -1;
    __syncthreads();
    const int k = kblk;
    if (k < 0) return;   // fully-padding block (uniform)

    // ---- stage expert weights ----
    for (int i = t; i < 1008; i += 256) {
        const int cf = i / 9, tap = i - cf * 9;
        wcs[i] = enc_conv_w[(size_t)k * 1008 + i] * conv_mask[tap];
        wtr[(cf >> 3) * WTSTR + tap * 8 + (cf & 7)] = dec_tconv_w[(size_t)k * 1008 + i];
    }
    for (int i = t; i < 1792; i += 256) decb[i] = dec_dense_b[(size_t)k * 1792 + i];
    if (t < 112) encb[t] = enc_dense_b[k * 112 + t];
    if (t < NG)  tcb[t]  = dec_tconv_b[k * NG + t];
    __syncthreads();

    // ---- P1: masked conv (7 live taps) + ReLU + 2x2 maxpool ----
    if (t < 224) {
        const int cc = t >> 1, h = t & 1;
        const int g = cc >> 3, ch = cc & 7;
        const float* wp = wcs + cc * 9;
        const float w0 = wp[0], w1 = wp[1], w3 = wp[3], w4 = wp[4],
                    w5 = wp[5], w7 = wp[7], w8 = wp[8];
        for (int b = 0; b < BW; ++b) {
            if (ids[b] < 0) break;
            const float* xg = x + (size_t)ids[b] * 896 + g * 64;
            float res[8];
            #pragma unroll
            for (int prl = 0; prl < 2; ++prl) {
                float rr[4][10];
                #pragma unroll
                for (int rwi = 0; rwi < 4; ++rwi) {
                    const int R = 4 * h + 2 * prl - 1 + rwi;
                    rr[rwi][0] = 0.f; rr[rwi][9] = 0.f;
                    if (R >= 0 && R < 8) {
                        const float4 a = *(const float4*)(xg + R * 8);
                        const float4 c = *(const float4*)(xg + R * 8 + 4);
                        rr[rwi][1] = a.x; rr[rwi][2] = a.y; rr[rwi][3] = a.z; rr[rwi][4] = a.w;
                        rr[rwi][5] = c.x; rr[rwi][6] = c.y; rr[rwi][7] = c.z; rr[rwi][8] = c.w;
                    } else {
                        #pragma unroll
                        for (int q = 1; q < 9; ++q) rr[rwi][q] = 0.f;
                    }
                }
                #pragma unroll
                for (int pc = 0; pc < 4; ++pc) {
                    float mx = 0.f;
                    #pragma unroll
                    for (int rl = 0; rl < 2; ++rl) {
                        #pragma unroll
                        for (int cl = 0; cl < 2; ++cl) {
                            const int jc = 2 * pc + cl + 1;
                            const float s =
                                rr[rl][jc - 1] * w0 + rr[rl][jc] * w1 +
                                rr[rl + 1][jc - 1] * w3 + rr[rl + 1][jc] * w4 + rr[rl + 1][jc + 1] * w5 +
                                rr[rl + 2][jc] * w7 + rr[rl + 2][jc + 1] * w8;
                            mx = fmaxf(mx, s);
                        }
                    }
                    res[prl * 4 + pc] = mx;
                }
            }
            float4* fo = (float4*)(&feat[b][g * FSTR + ch * 16 + 8 * h]);
            fo[0] = make_float4(res[0], res[1], res[2], res[3]);
            fo[1] = make_float4(res[4], res[5], res[6], res[7]);
        }
    }
    __syncthreads();

    // ---- P2: z = relu(encW . feat + b); W row loaded once per BW wafers ----
    if (t < 224) {
        const int g = t >> 4, r = t & 15, o = r >> 1, hh = r & 1;
        const float4* wrow = (const float4*)(enc_dense_w
                              + (((size_t)k * NG + g) * 8 + o) * 128 + hh * 64);
        float acc[BW];
        #pragma unroll
        for (int b = 0; b < BW; ++b) acc[b] = 0.f;
        #pragma unroll
        for (int q = 0; q < 4; ++q) {
            const float4 wA = wrow[q * 4 + 0], wB = wrow[q * 4 + 1],
                         wC = wrow[q * 4 + 2], wD = wrow[q * 4 + 3];
            #pragma unroll
            for (int b = 0; b < BW; ++b) {
                const float4* fp = (const float4*)(&feat[b][g * FSTR + hh * 64 + q * 16]);
                const float4 fA = fp[0], fB = fp[1], fC = fp[2], fD = fp[3];
                acc[b] += wA.x*fA.x + wA.y*fA.y + wA.z*fA.z + wA.w*fA.w
                        + wB.x*fB.x + wB.y*fB.y + wB.z*fB.z + wB.w*fB.w
                        + wC.x*fC.x + wC.y*fC.y + wC.z*fC.z + wC.w*fC.w
                        + wD.x*fD.x + wD.y*fD.y + wD.z*fD.z + wD.w*fD.w;
            }
        }
        #pragma unroll
        for (int b = 0; b < BW; ++b) acc[b] += __shfl_xor(acc[b], 1);
        if (hh == 0) {
            const float eb = encb[g * 8 + o];
            #pragma unroll
            for (int b = 0; b < BW; ++b)
                zsb[b][g * 8 + o] = fmaxf(acc[b] + eb, 0.f);
        }
    }
    __syncthreads();

    // ---- P3: y[g][p][c] = relu(decW[g, c*16+p, :] . z + b); W loaded once per BW ----
    if (t < 224) {
        const int g = t >> 4, p = t & 15;
        const float* wbase = dec_dense_w + ((size_t)k * NG + g) * 1024;
        #pragma unroll
        for (int cp = 0; cp < 4; ++cp) {
            const int c0 = 2 * cp, c1 = 2 * cp + 1;
            const float4* w0 = (const float4*)(wbase + (c0 * 16 + p) * 8);
            const float4* w1 = (const float4*)(wbase + (c1 * 16 + p) * 8);
            const float4 w0a = w0[0], w0b = w0[1];
            const float4 w1a = w1[0], w1b = w1[1];
            const float b0 = decb[g * 128 + c0 * 16 + p];
            const float b1 = decb[g * 128 + c1 * 16 + p];
            #pragma unroll
            for (int b = 0; b < BW; ++b) {
                const float4 za = *(const float4*)(&zsb[b][g * 8]);
                const float4 zb = *(const float4*)(&zsb[b][g * 8 + 4]);
                feat[b][g * FSTR + p * 8 + c0] = fmaxf(dot8(w0a, w0b, za, zb) + b0, 0.f);
                feat[b][g * FSTR + p * 8 + c1] = fmaxf(dot8(w1a, w1b, za, zb) + b1, 0.f);
            }
        }
    }
    __syncthreads();

    // ---- P4: grouped ConvTranspose2d + bias + ReLU, coalesced writes ----
    for (int idx = t; idx < 896; idx += 256) {
        const int g = idx >> 6, pix = idx & 63;
        const int oi = pix >> 3, oj = pix & 7;
        int nti = 1, iA, kiA, iB = 0, kiB = 0;
        if ((oi & 1) == 0) { iA = oi >> 1; kiA = 1; }
        else { iA = (oi - 1) >> 1; kiA = 2; if (oi < 7) { nti = 2; iB = (oi + 1) >> 1; kiB = 0; } }
        int ntj = 1, jA, kjA, jB = 0, kjB = 0;
        if ((oj & 1) == 0) { jA = oj >> 1; kjA = 1; }
        else { jA = (oj - 1) >> 1; kjA = 2; if (oj < 7) { ntj = 2; jB = (oj + 1) >> 1; kjB = 0; } }

        const float* wg = wtr + g * WTSTR;
        const float bias = tcb[g];
        #pragma unroll
        for (int b = 0; b < BW; ++b) {
            if (ids[b] < 0) break;
            const float* yg = &feat[b][g * FSTR];
            float acc = bias;
            for (int a_ = 0; a_ < nti; ++a_) {
                const int i  = a_ ? iB : iA;
                const int ki = a_ ? kiB : kiA;
                for (int b_ = 0; b_ < ntj; ++b_) {
                    const int j  = b_ ? jB : jA;
                    const int kj = b_ ? kjB : kjA;
                    const float4* wv = (const float4*)(wg + (ki * 3 + kj) * 8);
                    const float4* yv = (const float4*)(yg + (i * 4 + j) * 8);
                    acc += dot8(wv[0], wv[1], yv[0], yv[1]);
                }
            }
            out[(size_t)ids[b] * 896 + idx] = fmaxf(acc, 0.f);
        }
    }
}

extern "C" void kernel_launch(void* const* d_in, const int* in_sizes, int n_in,
                              void* d_out, int out_size, void* d_ws, size_t ws_size,
                              hipStream_t stream) {
    const float* x            = (const float*)d_in[0];
    const int*   keys         = (const int*)d_in[1];
    const float* conv_mask    = (const float*)d_in[2];
    const float* enc_conv_w   = (const float*)d_in[3];
    const float* enc_dense_w  = (const float*)d_in[4];
    const float* enc_dense_b  = (const float*)d_in[5];
    const float* dec_dense_w  = (const float*)d_in[6];
    const float* dec_dense_b  = (const float*)d_in[7];
    const float* dec_tconv_w  = (const float*)d_in[8];
    const float* dec_tconv_b  = (const float*)d_in[9];
    float* out = (float*)d_out;

    const int N = in_sizes[0] / (NG * 64);          // 4096
    int* wsI = (int*)d_ws;

    hipMemsetAsync(wsI, 0, 64 * sizeof(int), stream);                              // counts+cursors
    hipMemsetAsync(wsI + 64, 0xFF, (size_t)(N + NE * BW + BW) * sizeof(int), stream); // sorted = -1

    const int nb256 = (N + 255) / 256;
    hist_kernel<<<nb256, 256, 0, stream>>>(keys, N, wsI);
    scan_kernel<<<1, 64, 0, stream>>>(wsI);
    scatter_kernel<<<nb256, 256, 0, stream>>>(keys, N, wsI);

    const int NB = (N + NE * (BW - 1) + BW - 1) / BW;   // 1036 for N=4096
    ae_main<<<NB, 256, 0, stream>>>(
        x, keys, conv_mask, enc_conv_w, enc_dense_w, enc_dense_b,
        dec_dense_w, dec_dense_b, dec_tconv_w, dec_tconv_b, wsI, out);
}

// Round 5
// 39.811 us; speedup vs baseline: 2.0121x; 2.0121x over previous
//
#include <hip/hip_runtime.h>

#define NG 14
#define NE 16
#define BW 4
#define FSTR 132      // feat/y per-group stride (floats)
#define ZSTR 116      // z per-wafer stride
#define WTSTR 84      // tconv w: 10 rows (9 real + 1 zero) * 8 ch + 4 pad

__device__ __forceinline__ float dot8(float4 wa, float4 wb, float4 ya, float4 yb) {
    return wa.x*ya.x + wa.y*ya.y + wa.z*ya.z + wa.w*ya.w
         + wb.x*yb.x + wb.y*yb.y + wb.z*yb.z + wb.w*yb.w;
}

__global__ __launch_bounds__(1024) void bin_kernel(const int* __restrict__ keys, int N,
                                                   int NBW, int* __restrict__ sorted) {
    __shared__ int hist[NE], offs[NE], cur[NE];
    const int t = threadIdx.x;
    if (t < NE) { hist[t] = 0; cur[t] = 0; }
    for (int i = t; i < NBW; i += 1024) sorted[i] = -1;
    __syncthreads();
    for (int i = t; i < N; i += 1024) atomicAdd(&hist[keys[i]], 1);
    __syncthreads();
    if (t == 0) {
        int run = 0;
        for (int e = 0; e < NE; ++e) { offs[e] = run; run += (hist[e] + BW - 1) & ~(BW - 1); }
    }
    __syncthreads();
    for (int i = t; i < N; i += 1024) {
        const int e = keys[i];
        const int p = atomicAdd(&cur[e], 1);
        sorted[offs[e] + p] = i;
    }
}

__global__ __launch_bounds__(256, 4) void ae_main(
    const float* __restrict__ x,
    const int*   __restrict__ keys,
    const float* __restrict__ conv_mask,
    const float* __restrict__ enc_conv_w,
    const float* __restrict__ enc_dense_w,
    const float* __restrict__ enc_dense_b,
    const float* __restrict__ dec_dense_w,
    const float* __restrict__ dec_dense_b,
    const float* __restrict__ dec_tconv_w,
    const float* __restrict__ dec_tconv_b,
    const int*   __restrict__ sorted,
    float* __restrict__ out)
{
    const int t = threadIdx.x;

    __shared__ float feat[BW][NG * FSTR];   // conv feat, later overwritten by y [g][p*8+c]
    __shared__ float zsb[BW][ZSTR];
    __shared__ float wtr[NG * WTSTR];       // tconv w transposed [g][row*8+c]; row 9 = zeros

    const int4 idv = *(const int4*)(sorted + blockIdx.x * 4);
    const int i0 = idv.x;
    if (i0 < 0) return;
    const int k = keys[i0];
    const int idr[BW] = { i0,
                          idv.y < 0 ? i0 : idv.y,
                          idv.z < 0 ? i0 : idv.z,
                          idv.w < 0 ? i0 : idv.w };
    const int idw[BW] = { idv.x, idv.y, idv.z, idv.w };

    // ---- stage tconv weights transposed (+ zero row 9); no barrier needed until P4 ----
    for (int i = t; i < 1008; i += 256) {
        const int cf = i / 9, tap = i - cf * 9;
        wtr[(cf >> 3) * WTSTR + tap * 8 + (cf & 7)] = dec_tconv_w[(size_t)k * 1008 + i];
    }
    if (t < 112) wtr[(t >> 3) * WTSTR + 72 + (t & 7)] = 0.f;

    // ---- P1: masked conv (7 live taps) + ReLU + 2x2 maxpool ----
    if (t < 224) {
        const int cc = t >> 1, h = t & 1, g = cc >> 3, ch = cc & 7;
        const float* wp = enc_conv_w + (size_t)k * 1008 + cc * 9;
        const float w0 = wp[0]*conv_mask[0], w1 = wp[1]*conv_mask[1],
                    w3 = wp[3]*conv_mask[3], w4 = wp[4]*conv_mask[4], w5 = wp[5]*conv_mask[5],
                    w7 = wp[7]*conv_mask[7], w8 = wp[8]*conv_mask[8];
        const float z0 = (h == 0) ? 0.f : 1.f;   // row R=-1 invalid when h==0
        const float z5 = (h == 1) ? 0.f : 1.f;   // row R=8 invalid when h==1
        #pragma unroll
        for (int b = 0; b < BW; ++b) {
            const float* xg = x + (size_t)idr[b] * 896 + g * 64;
            float xr[6][10];
            #pragma unroll
            for (int rw = 0; rw < 6; ++rw) {
                const int R = 4 * h - 1 + rw;
                const int Rc = (R < 0) ? 0 : (R > 7 ? 7 : R);
                const float4 a = *(const float4*)(xg + Rc * 8);
                const float4 c = *(const float4*)(xg + Rc * 8 + 4);
                xr[rw][0] = 0.f; xr[rw][9] = 0.f;
                xr[rw][1] = a.x; xr[rw][2] = a.y; xr[rw][3] = a.z; xr[rw][4] = a.w;
                xr[rw][5] = c.x; xr[rw][6] = c.y; xr[rw][7] = c.z; xr[rw][8] = c.w;
            }
            #pragma unroll
            for (int j = 1; j < 9; ++j) { xr[0][j] *= z0; xr[5][j] *= z5; }
            #pragma unroll
            for (int prl = 0; prl < 2; ++prl) {
                const int r0 = 2 * prl;
                float res[4];
                #pragma unroll
                for (int pc = 0; pc < 4; ++pc) {
                    float mx = 0.f;
                    #pragma unroll
                    for (int rl = 0; rl < 2; ++rl) {
                        #pragma unroll
                        for (int cl = 0; cl < 2; ++cl) {
                            const int jc = 2 * pc + cl + 1;
                            const float s =
                                xr[r0+rl][jc-1]*w0 + xr[r0+rl][jc]*w1 +
                                xr[r0+rl+1][jc-1]*w3 + xr[r0+rl+1][jc]*w4 + xr[r0+rl+1][jc+1]*w5 +
                                xr[r0+rl+2][jc]*w7 + xr[r0+rl+2][jc+1]*w8;
                            mx = fmaxf(mx, s);
                        }
                    }
                    res[pc] = mx;
                }
                *(float4*)(&feat[b][g*FSTR + ch*16 + 8*h + 4*prl]) =
                    make_float4(res[0], res[1], res[2], res[3]);
            }
        }
    }
    __syncthreads();

    // ---- P2: z = relu(encW . feat + b); weight row loaded once for 4 wafers ----
    if (t < 224) {
        const int g = t >> 4, r = t & 15, o = r >> 1, hh = r & 1;
        const float4* wrow = (const float4*)(enc_dense_w
                              + (((size_t)k * NG + g) * 8 + o) * 128 + hh * 64);
        float acc[BW] = {0.f, 0.f, 0.f, 0.f};
        #pragma unroll
        for (int q = 0; q < 4; ++q) {
            const float4 wA = wrow[q*4+0], wB = wrow[q*4+1], wC = wrow[q*4+2], wD = wrow[q*4+3];
            #pragma unroll
            for (int b = 0; b < BW; ++b) {
                const float4* fp = (const float4*)(&feat[b][g*FSTR + hh*64 + q*16]);
                const float4 fA = fp[0], fB = fp[1], fC = fp[2], fD = fp[3];
                acc[b] += wA.x*fA.x + wA.y*fA.y + wA.z*fA.z + wA.w*fA.w
                        + wB.x*fB.x + wB.y*fB.y + wB.z*fB.z + wB.w*fB.w
                        + wC.x*fC.x + wC.y*fC.y + wC.z*fC.z + wC.w*fC.w
                        + wD.x*fD.x + wD.y*fD.y + wD.z*fD.z + wD.w*fD.w;
            }
        }
        #pragma unroll
        for (int b = 0; b < BW; ++b) acc[b] += __shfl_xor(acc[b], 1);
        if (hh == 0) {
            const float eb = enc_dense_b[k * 112 + g * 8 + o];
            #pragma unroll
            for (int b = 0; b < BW; ++b) zsb[b][g*8 + o] = fmaxf(acc[b] + eb, 0.f);
        }
    }
    __syncthreads();

    // ---- P3: y[g][p*8+c] = relu(decW . z + b), overwrites feat ----
    if (t < 224) {
        const int g = t >> 4, p = t & 15;
        const float* wbase = dec_dense_w + ((size_t)k * NG + g) * 1024;
        const float* bbase = dec_dense_b + (size_t)k * 1792 + g * 128;
        float4 za[BW], zb[BW];
        #pragma unroll
        for (int b = 0; b < BW; ++b) {
            za[b] = *(const float4*)(&zsb[b][g*8]);
            zb[b] = *(const float4*)(&zsb[b][g*8 + 4]);
        }
        #pragma unroll
        for (int cp = 0; cp < 4; ++cp) {
            const int c0 = 2*cp, c1 = c0 + 1;
            const float4* w0 = (const float4*)(wbase + (c0*16 + p) * 8);
            const float4* w1 = (const float4*)(wbase + (c1*16 + p) * 8);
            const float4 w0a = w0[0], w0b = w0[1], w1a = w1[0], w1b = w1[1];
            const float b0 = bbase[c0*16 + p], b1 = bbase[c1*16 + p];
            #pragma unroll
            for (int b = 0; b < BW; ++b) {
                feat[b][g*FSTR + p*8 + c0] = fmaxf(dot8(w0a, w0b, za[b], zb[b]) + b0, 0.f);
                feat[b][g*FSTR + p*8 + c1] = fmaxf(dot8(w1a, w1b, za[b], zb[b]) + b1, 0.f);
            }
        }
    }
    __syncthreads();

    // ---- P4: ConvTranspose2d via uniform 4-term taps (zero-weight row for invalid) ----
    if (t < 224) {
        const int g = t >> 4, oi = (t >> 1) & 7, h = t & 1;
        const float* wg = wtr + g * WTSTR;
        int iA, kiA, iB; bool vBi;
        if ((oi & 1) == 0) { iA = oi >> 1; kiA = 1; vBi = false; iB = iA; }
        else { iA = (oi - 1) >> 1; kiA = 2; vBi = (oi < 7); iB = vBi ? (oi + 1) >> 1 : iA; }
        const int rA = kiA * 3;                 // rows rA+0/1/2 for kj=0,1,2
        const int rB0 = vBi ? 0 : 9, rB1 = vBi ? 1 : 9, rB2 = vBi ? 2 : 9;  // kiB=0 rows or zero
        const float4 wA0a = *(const float4*)(wg + (rA+0)*8), wA0b = *(const float4*)(wg + (rA+0)*8 + 4);
        const float4 wA1a = *(const float4*)(wg + (rA+1)*8), wA1b = *(const float4*)(wg + (rA+1)*8 + 4);
        const float4 wA2a = *(const float4*)(wg + (rA+2)*8), wA2b = *(const float4*)(wg + (rA+2)*8 + 4);
        const float4 wB0a = *(const float4*)(wg + rB0*8), wB0b = *(const float4*)(wg + rB0*8 + 4);
        const float4 wB1a = *(const float4*)(wg + rB1*8), wB1b = *(const float4*)(wg + rB1*8 + 4);
        const float4 wB2a = *(const float4*)(wg + rB2*8), wB2b = *(const float4*)(wg + rB2*8 + 4);
        const int j0 = 2*h, j1 = 2*h + 1, j2 = (h == 0) ? 2 : 3;   // j2 clamped; sel3 zeroes it for h=1
        const float sel3 = (h == 0) ? 1.f : 0.f;
        const float bias = dec_tconv_b[k * NG + g];
        #pragma unroll
        for (int b = 0; b < BW; ++b) {
            const float* yg = &feat[b][g * FSTR];
            const float4 yA0a = *(const float4*)(yg + (iA*4+j0)*8), yA0b = *(const float4*)(yg + (iA*4+j0)*8 + 4);
            const float4 yA1a = *(const float4*)(yg + (iA*4+j1)*8), yA1b = *(const float4*)(yg + (iA*4+j1)*8 + 4);
            const float4 yA2a = *(const float4*)(yg + (iA*4+j2)*8), yA2b = *(const float4*)(yg + (iA*4+j2)*8 + 4);
            const float4 yB0a = *(const float4*)(yg + (iB*4+j0)*8), yB0b = *(const float4*)(yg + (iB*4+j0)*8 + 4);
            const float4 yB1a = *(const float4*)(yg + (iB*4+j1)*8), yB1b = *(const float4*)(yg + (iB*4+j1)*8 + 4);
            const float4 yB2a = *(const float4*)(yg + (iB*4+j2)*8), yB2b = *(const float4*)(yg + (iB*4+j2)*8 + 4);
            const float c0 = bias + dot8(wA1a,wA1b,yA0a,yA0b) + dot8(wB1a,wB1b,yB0a,yB0b);
            const float c1 = bias + dot8(wA2a,wA2b,yA0a,yA0b) + dot8(wA0a,wA0b,yA1a,yA1b)
                                  + dot8(wB2a,wB2b,yB0a,yB0b) + dot8(wB0a,wB0b,yB1a,yB1b);
            const float c2 = bias + dot8(wA1a,wA1b,yA1a,yA1b) + dot8(wB1a,wB1b,yB1a,yB1b);
            const float c3 = bias + dot8(wA2a,wA2b,yA1a,yA1b) + dot8(wB2a,wB2b,yB1a,yB1b)
                           + sel3 * (dot8(wA0a,wA0b,yA2a,yA2b) + dot8(wB0a,wB0b,yB2a,yB2b));
            if (idw[b] >= 0) {
                *(float4*)(out + (size_t)idw[b]*896 + g*64 + oi*8 + 4*h) =
                    make_float4(fmaxf(c0,0.f), fmaxf(c1,0.f), fmaxf(c2,0.f), fmaxf(c3,0.f));
            }
        }
    }
}

extern "C" void kernel_launch(void* const* d_in, const int* in_sizes, int n_in,
                              void* d_out, int out_size, void* d_ws, size_t ws_size,
                              hipStream_t stream) {
    const float* x            = (const float*)d_in[0];
    const int*   keys         = (const int*)d_in[1];
    const float* conv_mask    = (const float*)d_in[2];
    const float* enc_conv_w   = (const float*)d_in[3];
    const float* enc_dense_w  = (const float*)d_in[4];
    const float* enc_dense_b  = (const float*)d_in[5];
    const float* dec_dense_w  = (const float*)d_in[6];
    const float* dec_dense_b  = (const float*)d_in[7];
    const float* dec_tconv_w  = (const float*)d_in[8];
    const float* dec_tconv_b  = (const float*)d_in[9];
    float* out = (float*)d_out;

    const int N = in_sizes[0] / (NG * 64);                 // 4096
    const int NB = (N + NE * (BW - 1) + BW - 1) / BW;      // 1036
    int* sorted = (int*)d_ws;

    bin_kernel<<<1, 1024, 0, stream>>>(keys, N, NB * BW, sorted);
    ae_main<<<NB, 256, 0, stream>>>(
        x, keys, conv_mask, enc_conv_w, enc_dense_w, enc_dense_b,
        dec_dense_w, dec_dense_b, dec_tconv_w, dec_tconv_b, sorted, out);
}